// Round 2
// baseline (540.283 us; speedup 1.0000x reference)
//
#include <hip/hip_runtime.h>
#include <stdint.h>

typedef unsigned short u16;
typedef __attribute__((ext_vector_type(8))) short bf16x8;
typedef __attribute__((ext_vector_type(4))) short s16x4;
typedef __attribute__((ext_vector_type(4))) float f32x4;

#define MFMA16(a,b,c) __builtin_amdgcn_mfma_f32_16x16x32_bf16((a),(b),(c),0,0,0)

__device__ __forceinline__ u16 f2bf(float f) {
  union { float f; uint32_t u; } v; v.f = f;
  return (u16)((v.u + 0x7fffu + ((v.u >> 16) & 1u)) >> 16);
}

// ---------- kernel 1: cast hidden_states fp32 -> bf16 ----------
__global__ void k_cast(const float* __restrict__ src, u16* __restrict__ dst, int n8) {
  int idx = blockIdx.x * 256 + threadIdx.x;
  if (idx >= n8) return;
  const float4* s = (const float4*)src + (size_t)idx * 2;
  float4 a = s[0], b = s[1];
  bf16x8 o;
  o[0] = (short)f2bf(a.x); o[1] = (short)f2bf(a.y);
  o[2] = (short)f2bf(a.z); o[3] = (short)f2bf(a.w);
  o[4] = (short)f2bf(b.x); o[5] = (short)f2bf(b.y);
  o[6] = (short)f2bf(b.z); o[7] = (short)f2bf(b.w);
  *(bf16x8*)(dst + (size_t)idx * 8) = o;
}

// ---------- kernel 2: transpose+cast a 1024x1024 weight: Wt[j][d] = bf16(W[d][j]) ----------
__global__ void k_wtrans(const float* __restrict__ W, u16* __restrict__ Wt) {
  __shared__ u16 tile[32][33];
  int bd = blockIdx.x >> 5, bj = blockIdx.x & 31;
  int tx = threadIdx.x & 31, ty = threadIdx.x >> 5;  // ty 0..7
#pragma unroll
  for (int i = 0; i < 32; i += 8)
    tile[ty + i][tx] = f2bf(W[(size_t)(bd * 32 + ty + i) * 1024 + bj * 32 + tx]);
  __syncthreads();
#pragma unroll
  for (int i = 0; i < 32; i += 8)
    Wt[(size_t)(bj * 32 + ty + i) * 1024 + bd * 32 + tx] = tile[tx][ty + i];
}

// ---------- kernel 3: zero output ----------
__global__ void k_zero(float4* __restrict__ p, int n4) {
  int idx = blockIdx.x * 256 + threadIdx.x;
  if (idx < n4) p[idx] = make_float4(0.f, 0.f, 0.f, 0.f);
}

// ---------- kernel 4: fused QKV GEMM (bf16 MFMA, 128x128 tile) ----------
__global__ __launch_bounds__(256, 2) void k_qkv(
    const u16* __restrict__ hsb, const u16* __restrict__ Wt,
    const float* __restrict__ bq, const float* __restrict__ bk, const float* __restrict__ bv,
    u16* __restrict__ Qb, u16* __restrict__ Kb, u16* __restrict__ Vt) {
  __shared__ u16 a_lds[128][72];
  __shared__ u16 b_lds[128][72];
  const int tid = threadIdx.x;
  const int lane = tid & 63, wid = tid >> 6;
  const int l15 = lane & 15, quad = lane >> 4;
  const int wr = wid >> 1, wc = wid & 1;
  const int bx = blockIdx.x & 31;   // M tile
  const int by = blockIdx.x >> 5;   // 0..23
  const int Mbase = bx * 128;
  const int widx = by >> 3;               // 0=Q 1=K 2=V
  const int Nloc = (by & 7) * 128;        // col within the 1024-wide output

  f32x4 acc[4][4];
#pragma unroll
  for (int i = 0; i < 4; ++i)
#pragma unroll
    for (int j = 0; j < 4; ++j) acc[i][j] = (f32x4){0.f, 0.f, 0.f, 0.f};

  for (int kb = 0; kb < 16; ++kb) {
    const int kbase = kb * 64;
    __syncthreads();
#pragma unroll
    for (int i = 0; i < 4; ++i) {
      int ch = tid + i * 256;
      int r = ch >> 3, c = (ch & 7) * 8;
      *(bf16x8*)&a_lds[r][c] =
          *(const bf16x8*)(hsb + (size_t)(Mbase + r) * 1024 + kbase + c);
      *(bf16x8*)&b_lds[r][c] =
          *(const bf16x8*)(Wt + (size_t)widx * 1048576 + (size_t)(Nloc + r) * 1024 + kbase + c);
    }
    __syncthreads();
#pragma unroll
    for (int ks = 0; ks < 2; ++ks) {
      const int koff = ks * 32 + quad * 8;
      bf16x8 af[4], bfr[4];
#pragma unroll
      for (int mt = 0; mt < 4; ++mt) af[mt] = *(const bf16x8*)&a_lds[wr * 64 + mt * 16 + l15][koff];
#pragma unroll
      for (int nt = 0; nt < 4; ++nt) bfr[nt] = *(const bf16x8*)&b_lds[wc * 64 + nt * 16 + l15][koff];
#pragma unroll
      for (int mt = 0; mt < 4; ++mt)
#pragma unroll
        for (int nt = 0; nt < 4; ++nt)
          acc[mt][nt] = MFMA16(af[mt], bfr[nt], acc[mt][nt]);
    }
  }
  const float* bias = (widx == 0) ? bq : ((widx == 1) ? bk : bv);
#pragma unroll
  for (int nt = 0; nt < 4; ++nt) {
    const int jloc = Nloc + wc * 64 + nt * 16 + l15;
    const float bias_v = bias[jloc];
#pragma unroll
    for (int mt = 0; mt < 4; ++mt) {
      const int Mr0 = Mbase + wr * 64 + mt * 16 + quad * 4;
      if (widx == 2) {
        const int b = Mr0 >> 11, mseq = Mr0 & 2047;
        const int g = jloc >> 7, h = jloc & 127;
        s16x4 pk;
#pragma unroll
        for (int r = 0; r < 4; ++r) pk[r] = (short)f2bf(acc[mt][nt][r] + bias_v);
        *(s16x4*)(Vt + (((size_t)b * 8 + g) * 128 + h) * 2048 + mseq) = pk;
      } else {
        u16* dst = (widx == 0) ? Qb : Kb;
#pragma unroll
        for (int r = 0; r < 4; ++r)
          dst[(size_t)(Mr0 + r) * 1024 + jloc] = f2bf(acc[mt][nt][r] + bias_v);
      }
    }
  }
}

// ---------- kernel 5: grouped attention, v2 ----------
// grid 512 = 2 mc x 2 b x 128 ntiles; 512 threads = 8 waves, 2 blocks/CU.
// Block: n-tile of 16 (Q tile 32 KB in LDS, xor-swizzled), m-chunk of 1024.
// Per it (256 m): wave w computes S^T[32m x 16n x 8g] (m rows = w*32..),
// softmax over g in-register; P through LDS in 4 passes of 2 g; wave w owns
// PV for g=w (k=256 per it). Partial ctx combined across mc via atomicAdd.
__global__ __launch_bounds__(512, 4) void k_attn(
    const u16* __restrict__ Qb, const u16* __restrict__ Kb,
    const u16* __restrict__ Vt, float* __restrict__ out) {
  __shared__ u16 q_lds[16 * 1024];     // [n][h], 16B chunks xor-swizzled by (n&7)
  __shared__ u16 p_lds[2][16][264];    // [gg][n][m], pad 264: 4-bank row shift
  const int tid = threadIdx.x;
  const int w = tid >> 6;
  const int lane = tid & 63;
  const int l15 = lane & 15, quad = lane >> 4;
  const int bx = blockIdx.x;
  const int ntile = bx & 127;
  const int bcoord = (bx >> 7) & 1;
  const int mc = bx >> 8;
  const int nbase = ntile * 16;
  const size_t boff = (size_t)bcoord * 2048;

  // ---- stage Q tile (16 n x 1024 h) into LDS, swizzled ----
#pragma unroll
  for (int i = 0; i < 4; ++i) {
    int idx = tid + i * 512;
    int r = idx >> 7, c = idx & 127;
    bf16x8 v = *(const bf16x8*)(Qb + (boff + nbase + r) * 1024 + c * 8);
    *(bf16x8*)&q_lds[r * 1024 + ((c ^ (r & 7)) << 3)] = v;
  }
  __syncthreads();

  f32x4 cacc[8];
#pragma unroll
  for (int j = 0; j < 8; ++j) cacc[j] = (f32x4){0.f, 0.f, 0.f, 0.f};

  for (int it = 0; it < 4; ++it) {
    const int mbase = mc * 1024 + it * 256;
    // ---- scores: 32 m (2 frags) x 16 n x 8 g over 1024 h ----
    f32x4 sacc[2][8];
#pragma unroll
    for (int mf = 0; mf < 2; ++mf)
#pragma unroll
      for (int g = 0; g < 8; ++g) sacc[mf][g] = (f32x4){0.f, 0.f, 0.f, 0.f};

    const size_t krow0 = (boff + mbase + w * 32 + l15) * 1024;
#pragma unroll
    for (int g = 0; g < 8; ++g) {
#pragma unroll
      for (int ks = 0; ks < 4; ++ks) {
        const int hoff = g * 128 + ks * 32 + quad * 8;
        const int ch = (hoff >> 3) ^ (l15 & 7);
        bf16x8 qf = *(const bf16x8*)&q_lds[l15 * 1024 + (ch << 3)];
        bf16x8 kf0 = *(const bf16x8*)(Kb + krow0 + hoff);
        bf16x8 kf1 = *(const bf16x8*)(Kb + krow0 + 16 * 1024 + hoff);
        sacc[0][g] = MFMA16(kf0, qf, sacc[0][g]);  // D[m][n]
        sacc[1][g] = MFMA16(kf1, qf, sacc[1][g]);
      }
    }
    // ---- softmax over g (register-local) ----
#pragma unroll
    for (int mf = 0; mf < 2; ++mf)
#pragma unroll
      for (int r = 0; r < 4; ++r) {
        float s[8];
#pragma unroll
        for (int g = 0; g < 8; ++g) s[g] = sacc[mf][g][r] * 0.03125f;
        float mx = s[0];
#pragma unroll
        for (int g = 1; g < 8; ++g) mx = fmaxf(mx, s[g]);
        float sum = 0.f;
#pragma unroll
        for (int g = 0; g < 8; ++g) { s[g] = __expf(s[g] - mx); sum += s[g]; }
        const float rs = 1.0f / sum;
#pragma unroll
        for (int g = 0; g < 8; ++g) sacc[mf][g][r] = s[g] * rs;
      }
    // ---- P exchange (4 passes of 2 g) + PV by owner waves ----
#pragma unroll
    for (int gp = 0; gp < 4; ++gp) {
#pragma unroll
      for (int gg = 0; gg < 2; ++gg) {
        const int g = gp * 2 + gg;
#pragma unroll
        for (int mf = 0; mf < 2; ++mf) {
          s16x4 pk;
#pragma unroll
          for (int r = 0; r < 4; ++r) pk[r] = (short)f2bf(sacc[mf][g][r]);
          *(s16x4*)&p_lds[gg][l15][w * 32 + mf * 16 + quad * 4] = pk;
        }
      }
      __syncthreads();
      if ((w >> 1) == gp) {
        const int gg = w & 1;
        const size_t vbase = ((size_t)bcoord * 8 + w) * 128 * 2048;
#pragma unroll
        for (int ks = 0; ks < 8; ++ks) {
          bf16x8 pf = *(const bf16x8*)&p_lds[gg][l15][ks * 32 + quad * 8];
#pragma unroll
          for (int hc = 0; hc < 8; ++hc) {
            bf16x8 vf = *(const bf16x8*)(Vt + vbase + (size_t)(hc * 16 + l15) * 2048 +
                                         mbase + ks * 32 + quad * 8);
            cacc[hc] = MFMA16(pf, vf, cacc[hc]);  // D[n][h]
          }
        }
      }
      __syncthreads();
    }
  }
  // ---- epilogue: atomic accumulate partial ctx (disjoint mc chunks) ----
#pragma unroll
  for (int hc = 0; hc < 8; ++hc)
#pragma unroll
    for (int r = 0; r < 4; ++r) {
      const size_t oidx = (boff + nbase + quad * 4 + r) * 1024 + w * 128 + hc * 16 + l15;
      atomicAdd(out + oidx, cacc[hc][r]);
    }
}

extern "C" void kernel_launch(void* const* d_in, const int* in_sizes, int n_in,
                              void* d_out, int out_size, void* d_ws, size_t ws_size,
                              hipStream_t stream) {
  const float* hs = (const float*)d_in[0];
  const float* Wq = (const float*)d_in[1];
  const float* bq = (const float*)d_in[2];
  const float* Wk = (const float*)d_in[3];
  const float* bk = (const float*)d_in[4];
  const float* Wv = (const float*)d_in[5];
  const float* bv = (const float*)d_in[6];
  float* out = (float*)d_out;

  u16* ws = (u16*)d_ws;
  u16* hsb = ws;                   // 4096x1024
  u16* Wt  = ws + 4194304;         // 3 x 1024x1024 (j-major)
  u16* Qb  = ws + 7340032;         // [b][n][1024]
  u16* Kb  = ws + 11534336;        // [b][m][1024]
  u16* Vt  = ws + 15728640;        // [b][g][h][m] = [2][8][128][2048]

  k_cast<<<2048, 256, 0, stream>>>(hs, hsb, 524288);
  k_wtrans<<<1024, 256, 0, stream>>>(Wq, Wt);
  k_wtrans<<<1024, 256, 0, stream>>>(Wk, Wt + 1048576);
  k_wtrans<<<1024, 256, 0, stream>>>(Wv, Wt + 2097152);
  k_qkv<<<32 * 24, 256, 0, stream>>>(hsb, Wt, bq, bk, bv, Qb, Kb, Vt);
  k_zero<<<4096, 256, 0, stream>>>((float4*)out, 1048576);
  k_attn<<<512, 512, 0, stream>>>(Qb, Kb, Vt, out);
}

// Round 3
// 304.163 us; speedup vs baseline: 1.7763x; 1.7763x over previous
//
#include <hip/hip_runtime.h>
#include <stdint.h>

typedef unsigned short u16;
typedef __attribute__((ext_vector_type(8))) short bf16x8;
typedef __attribute__((ext_vector_type(4))) short s16x4;
typedef __attribute__((ext_vector_type(4))) float f32x4;

#define MFMA16(a,b,c) __builtin_amdgcn_mfma_f32_16x16x32_bf16((a),(b),(c),0,0,0)

__device__ __forceinline__ u16 f2bf(float f) {
  union { float f; uint32_t u; } v; v.f = f;
  return (u16)((v.u + 0x7fffu + ((v.u >> 16) & 1u)) >> 16);
}

// ---------- kernel 1: cast hidden_states fp32 -> bf16 ----------
__global__ void k_cast(const float* __restrict__ src, u16* __restrict__ dst, int n8) {
  int idx = blockIdx.x * 256 + threadIdx.x;
  if (idx >= n8) return;
  const float4* s = (const float4*)src + (size_t)idx * 2;
  float4 a = s[0], b = s[1];
  bf16x8 o;
  o[0] = (short)f2bf(a.x); o[1] = (short)f2bf(a.y);
  o[2] = (short)f2bf(a.z); o[3] = (short)f2bf(a.w);
  o[4] = (short)f2bf(b.x); o[5] = (short)f2bf(b.y);
  o[6] = (short)f2bf(b.z); o[7] = (short)f2bf(b.w);
  *(bf16x8*)(dst + (size_t)idx * 8) = o;
}

// ---------- kernel 2: transpose+cast weight: Wt[j][d] = bf16(W[d][j]) ----------
__global__ void k_wtrans(const float* __restrict__ W, u16* __restrict__ Wt) {
  __shared__ u16 tile[32][33];
  int bd = blockIdx.x >> 5, bj = blockIdx.x & 31;
  int tx = threadIdx.x & 31, ty = threadIdx.x >> 5;
#pragma unroll
  for (int i = 0; i < 32; i += 8)
    tile[ty + i][tx] = f2bf(W[(size_t)(bd * 32 + ty + i) * 1024 + bj * 32 + tx]);
  __syncthreads();
#pragma unroll
  for (int i = 0; i < 32; i += 8)
    Wt[(size_t)(bj * 32 + ty + i) * 1024 + bd * 32 + tx] = tile[tx][ty + i];
}

// ---------- kernel 3: zero output ----------
__global__ void k_zero(float4* __restrict__ p, int n4) {
  int idx = blockIdx.x * 256 + threadIdx.x;
  if (idx < n4) p[idx] = make_float4(0.f, 0.f, 0.f, 0.f);
}

// ---------- kernel 4: fused QKV GEMM (bf16 MFMA, 128x128 tile) ----------
__global__ __launch_bounds__(256, 2) void k_qkv(
    const u16* __restrict__ hsb, const u16* __restrict__ Wt,
    const float* __restrict__ bq, const float* __restrict__ bk, const float* __restrict__ bv,
    u16* __restrict__ Qb, u16* __restrict__ Kb, u16* __restrict__ Vt) {
  __shared__ u16 a_lds[128][72];
  __shared__ u16 b_lds[128][72];
  const int tid = threadIdx.x;
  const int lane = tid & 63, wid = tid >> 6;
  const int l15 = lane & 15, quad = lane >> 4;
  const int wr = wid >> 1, wc = wid & 1;
  const int bx = blockIdx.x & 31;
  const int by = blockIdx.x >> 5;
  const int Mbase = bx * 128;
  const int widx = by >> 3;               // 0=Q 1=K 2=V
  const int Nloc = (by & 7) * 128;

  f32x4 acc[4][4];
#pragma unroll
  for (int i = 0; i < 4; ++i)
#pragma unroll
    for (int j = 0; j < 4; ++j) acc[i][j] = (f32x4){0.f, 0.f, 0.f, 0.f};

  for (int kb = 0; kb < 16; ++kb) {
    const int kbase = kb * 64;
    __syncthreads();
#pragma unroll
    for (int i = 0; i < 4; ++i) {
      int ch = tid + i * 256;
      int r = ch >> 3, c = (ch & 7) * 8;
      *(bf16x8*)&a_lds[r][c] =
          *(const bf16x8*)(hsb + (size_t)(Mbase + r) * 1024 + kbase + c);
      *(bf16x8*)&b_lds[r][c] =
          *(const bf16x8*)(Wt + (size_t)widx * 1048576 + (size_t)(Nloc + r) * 1024 + kbase + c);
    }
    __syncthreads();
#pragma unroll
    for (int ks = 0; ks < 2; ++ks) {
      const int koff = ks * 32 + quad * 8;
      bf16x8 af[4], bfr[4];
#pragma unroll
      for (int mt = 0; mt < 4; ++mt) af[mt] = *(const bf16x8*)&a_lds[wr * 64 + mt * 16 + l15][koff];
#pragma unroll
      for (int nt = 0; nt < 4; ++nt) bfr[nt] = *(const bf16x8*)&b_lds[wc * 64 + nt * 16 + l15][koff];
#pragma unroll
      for (int mt = 0; mt < 4; ++mt)
#pragma unroll
        for (int nt = 0; nt < 4; ++nt)
          acc[mt][nt] = MFMA16(af[mt], bfr[nt], acc[mt][nt]);
    }
  }
  const float* bias = (widx == 0) ? bq : ((widx == 1) ? bk : bv);
#pragma unroll
  for (int nt = 0; nt < 4; ++nt) {
    const int jloc = Nloc + wc * 64 + nt * 16 + l15;
    const float bias_v = bias[jloc];
#pragma unroll
    for (int mt = 0; mt < 4; ++mt) {
      const int Mr0 = Mbase + wr * 64 + mt * 16 + quad * 4;
      if (widx == 2) {
        const int b = Mr0 >> 11, mseq = Mr0 & 2047;
        const int g = jloc >> 7, h = jloc & 127;
        s16x4 pk;
#pragma unroll
        for (int r = 0; r < 4; ++r) pk[r] = (short)f2bf(acc[mt][nt][r] + bias_v);
        *(s16x4*)(Vt + (((size_t)b * 8 + g) * 128 + h) * 2048 + mseq) = pk;
      } else {
        u16* dst = (widx == 0) ? Qb : Kb;
#pragma unroll
        for (int r = 0; r < 4; ++r)
          dst[(size_t)(Mr0 + r) * 1024 + jloc] = f2bf(acc[mt][nt][r] + bias_v);
      }
    }
  }
}

// ---------- kernel 5: scores + softmax-over-g, write Pt[b][g][n][m-half] bf16 ----------
// grid 1024 = 2b x 64nt x 8mt (mt = bx&7 -> same-K blocks pinned to one XCD).
// Block: 32 n (Q in LDS 64KB), 128 m (wave w owns rows w*16..), all 8 g.
// Wave: sacc[2 nf][8 g] f32x4 = 64 VGPRs; softmax over g register-local.
__global__ __launch_bounds__(512, 2) void k_score(
    const u16* __restrict__ Qb, const u16* __restrict__ Kb,
    u16* __restrict__ Pt, int mh) {
  __shared__ u16 q_lds[32 * 1024];  // [n][h], 16B chunks xor-swizzled by (n&7)
  const int tid = threadIdx.x;
  const int w = tid >> 6;
  const int lane = tid & 63;
  const int l15 = lane & 15, quad = lane >> 4;
  const int bx = blockIdx.x;
  const int mt = bx & 7;
  const int nt = (bx >> 3) & 63;
  const int bcoord = bx >> 9;
  const int nbase = nt * 32;
  const int mloc = mt * 128;            // m within half (0..1023)
  const int mglob = mh * 1024 + mloc;   // m within sequence
  const size_t boff = (size_t)bcoord * 2048;

  // stage Q tile 32 x 1024
#pragma unroll
  for (int i = 0; i < 8; ++i) {
    int idx = tid + i * 512;
    int r = idx >> 7, c = idx & 127;
    bf16x8 v = *(const bf16x8*)(Qb + (boff + nbase + r) * 1024 + c * 8);
    *(bf16x8*)&q_lds[r * 1024 + ((c ^ (r & 7)) << 3)] = v;
  }
  __syncthreads();

  f32x4 sacc[2][8];
#pragma unroll
  for (int nf = 0; nf < 2; ++nf)
#pragma unroll
    for (int g = 0; g < 8; ++g) sacc[nf][g] = (f32x4){0.f, 0.f, 0.f, 0.f};

  const size_t krow = (boff + mglob + w * 16 + l15) * 1024;
#pragma unroll
  for (int g = 0; g < 8; ++g) {
#pragma unroll
    for (int ks = 0; ks < 4; ++ks) {
      const int hoff = g * 128 + ks * 32 + quad * 8;
      bf16x8 kf = *(const bf16x8*)(Kb + krow + hoff);
#pragma unroll
      for (int nf = 0; nf < 2; ++nf) {
        const int row = nf * 16 + l15;
        bf16x8 qf = *(const bf16x8*)&q_lds[row * 1024 + (((hoff >> 3) ^ (row & 7)) << 3)];
        sacc[nf][g] = MFMA16(kf, qf, sacc[nf][g]);  // D[m][n]
      }
    }
  }
  // softmax over g (register-local)
#pragma unroll
  for (int nf = 0; nf < 2; ++nf)
#pragma unroll
    for (int r = 0; r < 4; ++r) {
      float s[8];
#pragma unroll
      for (int g = 0; g < 8; ++g) s[g] = sacc[nf][g][r] * 0.03125f;
      float mx = s[0];
#pragma unroll
      for (int g = 1; g < 8; ++g) mx = fmaxf(mx, s[g]);
      float sum = 0.f;
#pragma unroll
      for (int g = 0; g < 8; ++g) { s[g] = __expf(s[g] - mx); sum += s[g]; }
      const float rs = 1.0f / sum;
#pragma unroll
      for (int g = 0; g < 8; ++g) sacc[nf][g][r] = s[g] * rs;
    }
  // store Pt[b][g][n][m-half], m contiguous (A-operand-ready for k_pv)
  const int mcol = mloc + w * 16 + quad * 4;
#pragma unroll
  for (int g = 0; g < 8; ++g) {
    const size_t gbase = ((size_t)(bcoord * 8 + g) * 2048) * 1024;
#pragma unroll
    for (int nf = 0; nf < 2; ++nf) {
      s16x4 pk;
#pragma unroll
      for (int r = 0; r < 4; ++r) pk[r] = (short)f2bf(sacc[nf][g][r]);
      *(s16x4*)(Pt + gbase + (size_t)(nbase + nf * 16 + l15) * 1024 + mcol) = pk;
    }
  }
}

// ---------- kernel 6: PV GEMM: out[b][n][g*128+h] += P_g[n][m] * V_g[h][m] ----------
// grid 512 = 2b x 8g x 16mt x 2ksplit; 512 threads = 8 waves (2 wr x 4 wc).
// K-chunk = 512 per block (of this m-half); fp32 atomicAdd epilogue.
__global__ __launch_bounds__(512, 2) void k_pv(
    const u16* __restrict__ Pt, const u16* __restrict__ Vt,
    float* __restrict__ out, int mh) {
  __shared__ u16 a_lds[128][72];
  __shared__ u16 b_lds[128][72];
  const int tid = threadIdx.x;
  const int lane = tid & 63, wid = tid >> 6;
  const int l15 = lane & 15, quad = lane >> 4;
  const int wr = wid >> 2, wc = wid & 3;
  const int bx = blockIdx.x;
  const int ksp = bx & 1;
  const int mt = (bx >> 1) & 15;
  const int g = (bx >> 5) & 7;
  const int bcoord = bx >> 8;
  const int nbase = mt * 128;

  const size_t pbase = ((size_t)(bcoord * 8 + g) * 2048) * 1024;
  const size_t vbase = ((size_t)(bcoord * 8 + g) * 128) * 2048;
  const int kh0 = ksp * 512;            // within half (Pt cols)
  const int kg0 = mh * 1024 + kh0;      // within sequence (Vt cols)

  f32x4 acc[4][2];
#pragma unroll
  for (int i = 0; i < 4; ++i)
#pragma unroll
    for (int j = 0; j < 2; ++j) acc[i][j] = (f32x4){0.f, 0.f, 0.f, 0.f};

  for (int kb = 0; kb < 8; ++kb) {
    __syncthreads();
#pragma unroll
    for (int i = 0; i < 2; ++i) {
      int ch = tid + i * 512;
      int r = ch >> 3, c = (ch & 7) * 8;
      *(bf16x8*)&a_lds[r][c] =
          *(const bf16x8*)(Pt + pbase + (size_t)(nbase + r) * 1024 + kh0 + kb * 64 + c);
      *(bf16x8*)&b_lds[r][c] =
          *(const bf16x8*)(Vt + vbase + (size_t)r * 2048 + kg0 + kb * 64 + c);
    }
    __syncthreads();
#pragma unroll
    for (int ks = 0; ks < 2; ++ks) {
      const int koff = ks * 32 + quad * 8;
      bf16x8 af[4], bfr[2];
#pragma unroll
      for (int mf = 0; mf < 4; ++mf) af[mf] = *(const bf16x8*)&a_lds[wr * 64 + mf * 16 + l15][koff];
#pragma unroll
      for (int nf = 0; nf < 2; ++nf) bfr[nf] = *(const bf16x8*)&b_lds[wc * 32 + nf * 16 + l15][koff];
#pragma unroll
      for (int mf = 0; mf < 4; ++mf)
#pragma unroll
        for (int nf = 0; nf < 2; ++nf)
          acc[mf][nf] = MFMA16(af[mf], bfr[nf], acc[mf][nf]);
    }
  }
  // epilogue: atomic accumulate (ksplit x mh partials)
#pragma unroll
  for (int mf = 0; mf < 4; ++mf)
#pragma unroll
    for (int nf = 0; nf < 2; ++nf)
#pragma unroll
      for (int r = 0; r < 4; ++r) {
        const int nrow = nbase + wr * 64 + mf * 16 + quad * 4 + r;
        const int col = g * 128 + wc * 32 + nf * 16 + l15;
        atomicAdd(out + ((size_t)bcoord * 2048 + nrow) * 1024 + col, acc[mf][nf][r]);
      }
}

extern "C" void kernel_launch(void* const* d_in, const int* in_sizes, int n_in,
                              void* d_out, int out_size, void* d_ws, size_t ws_size,
                              hipStream_t stream) {
  const float* hs = (const float*)d_in[0];
  const float* Wq = (const float*)d_in[1];
  const float* bq = (const float*)d_in[2];
  const float* Wk = (const float*)d_in[3];
  const float* bk = (const float*)d_in[4];
  const float* Wv = (const float*)d_in[5];
  const float* bv = (const float*)d_in[6];
  float* out = (float*)d_out;

  u16* ws = (u16*)d_ws;
  u16* hsb = ws;                   // 4096x1024
  u16* Wt  = ws + 4194304;         // 3 x 1024x1024 (j-major)
  u16* Qb  = ws + 7340032;         // [b][n][1024]
  u16* Kb  = ws + 11534336;        // [b][m][1024]
  u16* Vt  = ws + 15728640;        // [b][g][h][m] = [2][8][128][2048]
  u16* Pt  = ws + 19922944;        // [b][g][n][m-half] = [2][8][2048][1024] (67 MB)

  k_cast<<<2048, 256, 0, stream>>>(hs, hsb, 524288);
  k_wtrans<<<1024, 256, 0, stream>>>(Wq, Wt);
  k_wtrans<<<1024, 256, 0, stream>>>(Wk, Wt + 1048576);
  k_wtrans<<<1024, 256, 0, stream>>>(Wv, Wt + 2097152);
  k_qkv<<<32 * 24, 256, 0, stream>>>(hsb, Wt, bq, bk, bv, Qb, Kb, Vt);
  k_zero<<<4096, 256, 0, stream>>>((float4*)out, 1048576);
  for (int mh = 0; mh < 2; ++mh) {
    k_score<<<1024, 512, 0, stream>>>(Qb, Kb, Pt, mh);
    k_pv<<<512, 512, 0, stream>>>(Pt, Vt, out, mh);
  }
}

// Round 4
// 295.626 us; speedup vs baseline: 1.8276x; 1.0289x over previous
//
#include <hip/hip_runtime.h>
#include <stdint.h>

typedef unsigned short u16;
typedef __attribute__((ext_vector_type(8))) short bf16x8;
typedef __attribute__((ext_vector_type(4))) short s16x4;
typedef __attribute__((ext_vector_type(4))) float f32x4;

#define MFMA16(a,b,c) __builtin_amdgcn_mfma_f32_16x16x32_bf16((a),(b),(c),0,0,0)

__device__ __forceinline__ u16 f2bf(float f) {
  union { float f; uint32_t u; } v; v.f = f;
  return (u16)((v.u + 0x7fffu + ((v.u >> 16) & 1u)) >> 16);
}

// async 16B global->LDS (lds dest = wave-uniform base + lane*16)
__device__ __forceinline__ void gload16(const void* g, void* l) {
  __builtin_amdgcn_global_load_lds((const __attribute__((address_space(1))) void*)g,
                                   (__attribute__((address_space(3))) void*)l, 16, 0, 0);
}

// Stage a 128x64 bf16 tile into lds[128*64] with chunk-xor swizzle.
// Physical chunk (r, pc) holds logical chunk (r, pc^(r&7)).
__device__ __forceinline__ void stage256(const u16* src, size_t stride, u16* lds, int tid) {
#pragma unroll
  for (int i = 0; i < 4; ++i) {
    const int L = i * 256 + tid;       // chunk 0..1023
    const int r = L >> 3, pc = L & 7;
    const int lc = pc ^ (r & 7);
    gload16(src + (size_t)r * stride + lc * 8, lds + (size_t)(i * 256 + (tid & ~63)) * 8);
  }
}
__device__ __forceinline__ void stage512(const u16* src, size_t stride, u16* lds, int tid) {
#pragma unroll
  for (int i = 0; i < 2; ++i) {
    const int L = i * 512 + tid;
    const int r = L >> 3, pc = L & 7;
    const int lc = pc ^ (r & 7);
    gload16(src + (size_t)r * stride + lc * 8, lds + (size_t)(i * 512 + (tid & ~63)) * 8);
  }
}
// read logical chunk kc of row from a swizzled 128x64 tile
#define TILE_AT(lds, row, kc) \
  (*(const bf16x8*)&(lds)[((((row) << 3) + ((kc) ^ ((row) & 7)))) << 3])

// ---------- kernel 1: cast hidden_states fp32 -> bf16 ----------
__global__ void k_cast(const float* __restrict__ src, u16* __restrict__ dst, int n8) {
  int idx = blockIdx.x * 256 + threadIdx.x;
  if (idx >= n8) return;
  const float4* s = (const float4*)src + (size_t)idx * 2;
  float4 a = s[0], b = s[1];
  bf16x8 o;
  o[0] = (short)f2bf(a.x); o[1] = (short)f2bf(a.y);
  o[2] = (short)f2bf(a.z); o[3] = (short)f2bf(a.w);
  o[4] = (short)f2bf(b.x); o[5] = (short)f2bf(b.y);
  o[6] = (short)f2bf(b.z); o[7] = (short)f2bf(b.w);
  *(bf16x8*)(dst + (size_t)idx * 8) = o;
}

// ---------- kernel 2: transpose+cast weight: Wt[j][d] = bf16(W[d][j]) ----------
__global__ void k_wtrans(const float* __restrict__ W, u16* __restrict__ Wt) {
  __shared__ u16 tile[32][33];
  int bd = blockIdx.x >> 5, bj = blockIdx.x & 31;
  int tx = threadIdx.x & 31, ty = threadIdx.x >> 5;
#pragma unroll
  for (int i = 0; i < 32; i += 8)
    tile[ty + i][tx] = f2bf(W[(size_t)(bd * 32 + ty + i) * 1024 + bj * 32 + tx]);
  __syncthreads();
#pragma unroll
  for (int i = 0; i < 32; i += 8)
    Wt[(size_t)(bj * 32 + ty + i) * 1024 + bd * 32 + tx] = tile[tx][ty + i];
}

// ---------- kernel 3: zero output ----------
__global__ void k_zero(float4* __restrict__ p, int n4) {
  int idx = blockIdx.x * 256 + threadIdx.x;
  if (idx < n4) p[idx] = make_float4(0.f, 0.f, 0.f, 0.f);
}

// ---------- kernel 4: fused QKV GEMM (async LDS staging) ----------
__global__ __launch_bounds__(256, 2) void k_qkv(
    const u16* __restrict__ hsb, const u16* __restrict__ Wt,
    const float* __restrict__ bq, const float* __restrict__ bk, const float* __restrict__ bv,
    u16* __restrict__ Qb, u16* __restrict__ Kb, u16* __restrict__ Vt) {
  __shared__ u16 a_lds[128 * 64];
  __shared__ u16 b_lds[128 * 64];
  const int tid = threadIdx.x;
  const int lane = tid & 63, wid = tid >> 6;
  const int l15 = lane & 15, quad = lane >> 4;
  const int wr = wid >> 1, wc = wid & 1;
  const int bx = blockIdx.x & 31;
  const int by = blockIdx.x >> 5;
  const int Mbase = bx * 128;
  const int widx = by >> 3;               // 0=Q 1=K 2=V
  const int Nloc = (by & 7) * 128;

  f32x4 acc[4][4];
#pragma unroll
  for (int i = 0; i < 4; ++i)
#pragma unroll
    for (int j = 0; j < 4; ++j) acc[i][j] = (f32x4){0.f, 0.f, 0.f, 0.f};

  const u16* asrc = hsb + (size_t)Mbase * 1024;
  const u16* bsrc = Wt + (size_t)widx * 1048576 + (size_t)Nloc * 1024;

  for (int kb = 0; kb < 16; ++kb) {
    __syncthreads();
    stage256(asrc + kb * 64, 1024, a_lds, tid);
    stage256(bsrc + kb * 64, 1024, b_lds, tid);
    __syncthreads();
#pragma unroll
    for (int ks = 0; ks < 2; ++ks) {
      const int kc = ks * 4 + quad;
      bf16x8 af[4], bfr[4];
#pragma unroll
      for (int mt = 0; mt < 4; ++mt) af[mt] = TILE_AT(a_lds, wr * 64 + mt * 16 + l15, kc);
#pragma unroll
      for (int nt = 0; nt < 4; ++nt) bfr[nt] = TILE_AT(b_lds, wc * 64 + nt * 16 + l15, kc);
#pragma unroll
      for (int mt = 0; mt < 4; ++mt)
#pragma unroll
        for (int nt = 0; nt < 4; ++nt)
          acc[mt][nt] = MFMA16(af[mt], bfr[nt], acc[mt][nt]);
    }
  }
  const float* bias = (widx == 0) ? bq : ((widx == 1) ? bk : bv);
#pragma unroll
  for (int nt = 0; nt < 4; ++nt) {
    const int jloc = Nloc + wc * 64 + nt * 16 + l15;
    const float bias_v = bias[jloc];
#pragma unroll
    for (int mt = 0; mt < 4; ++mt) {
      const int Mr0 = Mbase + wr * 64 + mt * 16 + quad * 4;
      if (widx == 2) {
        const int b = Mr0 >> 11, mseq = Mr0 & 2047;
        const int g = jloc >> 7, h = jloc & 127;
        s16x4 pk;
#pragma unroll
        for (int r = 0; r < 4; ++r) pk[r] = (short)f2bf(acc[mt][nt][r] + bias_v);
        *(s16x4*)(Vt + (((size_t)b * 8 + g) * 128 + h) * 2048 + mseq) = pk;
      } else {
        u16* dst = (widx == 0) ? Qb : Kb;
#pragma unroll
        for (int r = 0; r < 4; ++r)
          dst[(size_t)(Mr0 + r) * 1024 + jloc] = f2bf(acc[mt][nt][r] + bias_v);
      }
    }
  }
}

// ---------- kernel 5: scores + softmax-over-g -> Pt[b][g][n][m-half] ----------
// grid 1024 = 8mt (XCD-pinned) x 64nt x 2b; 8 waves; wave owns 16 m rows.
// kf pipeline: distance-1 prefetch of next g's 4 K fragments.
__global__ __launch_bounds__(512, 4) void k_score(
    const u16* __restrict__ Qb, const u16* __restrict__ Kb,
    u16* __restrict__ Pt, int mh) {
  __shared__ u16 q_lds[32 * 1024];  // [n][h], 16B chunks xor-swizzled by (n&7)
  const int tid = threadIdx.x;
  const int w = tid >> 6;
  const int lane = tid & 63;
  const int l15 = lane & 15, quad = lane >> 4;
  const int bx = blockIdx.x;
  const int mt = bx & 7;
  const int nt = (bx >> 3) & 63;
  const int bcoord = bx >> 9;
  const int nbase = nt * 32;
  const int mloc = mt * 128;
  const int mglob = mh * 1024 + mloc;
  const size_t boff = (size_t)bcoord * 2048;

  // stage Q tile 32 x 1024
#pragma unroll
  for (int i = 0; i < 8; ++i) {
    int idx = tid + i * 512;
    int r = idx >> 7, c = idx & 127;
    bf16x8 v = *(const bf16x8*)(Qb + (boff + nbase + r) * 1024 + c * 8);
    *(bf16x8*)&q_lds[r * 1024 + ((c ^ (r & 7)) << 3)] = v;
  }
  __syncthreads();

  f32x4 sacc[2][8];
#pragma unroll
  for (int nf = 0; nf < 2; ++nf)
#pragma unroll
    for (int g = 0; g < 8; ++g) sacc[nf][g] = (f32x4){0.f, 0.f, 0.f, 0.f};

  const u16* kp = Kb + (boff + mglob + w * 16 + l15) * 1024 + quad * 8;
  bf16x8 kbuf[2][4];
#pragma unroll
  for (int ks = 0; ks < 4; ++ks) kbuf[0][ks] = *(const bf16x8*)(kp + ks * 32);
#pragma unroll
  for (int g = 0; g < 8; ++g) {
    if (g < 7) {
#pragma unroll
      for (int ks = 0; ks < 4; ++ks)
        kbuf[(g + 1) & 1][ks] = *(const bf16x8*)(kp + (g + 1) * 128 + ks * 32);
    }
#pragma unroll
    for (int ks = 0; ks < 4; ++ks) {
      const int hoff = g * 128 + ks * 32 + quad * 8;
#pragma unroll
      for (int nf = 0; nf < 2; ++nf) {
        const int row = nf * 16 + l15;
        bf16x8 qf = *(const bf16x8*)&q_lds[row * 1024 + (((hoff >> 3) ^ (row & 7)) << 3)];
        sacc[nf][g] = MFMA16(kbuf[g & 1][ks], qf, sacc[nf][g]);  // D[m][n]
      }
    }
  }
  // softmax over g (register-local)
#pragma unroll
  for (int nf = 0; nf < 2; ++nf)
#pragma unroll
    for (int r = 0; r < 4; ++r) {
      float s[8];
#pragma unroll
      for (int g = 0; g < 8; ++g) s[g] = sacc[nf][g][r] * 0.03125f;
      float mx = s[0];
#pragma unroll
      for (int g = 1; g < 8; ++g) mx = fmaxf(mx, s[g]);
      float sum = 0.f;
#pragma unroll
      for (int g = 0; g < 8; ++g) { s[g] = __expf(s[g] - mx); sum += s[g]; }
      const float rs = 1.0f / sum;
#pragma unroll
      for (int g = 0; g < 8; ++g) sacc[nf][g][r] = s[g] * rs;
    }
  // store Pt[b][g][n][m-half]
  const int mcol = mloc + w * 16 + quad * 4;
#pragma unroll
  for (int g = 0; g < 8; ++g) {
    const size_t gbase = ((size_t)(bcoord * 8 + g) * 2048) * 1024;
#pragma unroll
    for (int nf = 0; nf < 2; ++nf) {
      s16x4 pk;
#pragma unroll
      for (int r = 0; r < 4; ++r) pk[r] = (short)f2bf(sacc[nf][g][r]);
      *(s16x4*)(Pt + gbase + (size_t)(nbase + nf * 16 + l15) * 1024 + mcol) = pk;
    }
  }
}

// ---------- kernel 6: PV GEMM, async LDS staging ----------
// grid 512 = 8g (XCD-pinned) x 2ksp x 16mt x 2b; 512 thr = 8 waves (4 wr x 2 wc).
__global__ __launch_bounds__(512, 4) void k_pv(
    const u16* __restrict__ Pt, const u16* __restrict__ Vt,
    float* __restrict__ out, int mh) {
  __shared__ u16 a_lds[128 * 64];
  __shared__ u16 b_lds[128 * 64];
  const int tid = threadIdx.x;
  const int lane = tid & 63, wid = tid >> 6;
  const int l15 = lane & 15, quad = lane >> 4;
  const int wr = wid >> 1, wc = wid & 1;
  const int bx = blockIdx.x;
  const int g = bx & 7;
  const int ksp = (bx >> 3) & 1;
  const int mt = (bx >> 4) & 15;
  const int bcoord = bx >> 8;
  const int nbase = mt * 128;
  const int kh0 = ksp * 512;

  const u16* asrc = Pt + (size_t)(bcoord * 8 + g) * 2048 * 1024 + (size_t)nbase * 1024 + kh0;
  const u16* bsrc = Vt + (size_t)(bcoord * 8 + g) * 128 * 2048 + mh * 1024 + kh0;

  f32x4 acc[2][4];
#pragma unroll
  for (int i = 0; i < 2; ++i)
#pragma unroll
    for (int j = 0; j < 4; ++j) acc[i][j] = (f32x4){0.f, 0.f, 0.f, 0.f};

  for (int kb = 0; kb < 8; ++kb) {
    __syncthreads();
    stage512(asrc + kb * 64, 1024, a_lds, tid);
    stage512(bsrc + kb * 64, 2048, b_lds, tid);
    __syncthreads();
#pragma unroll
    for (int ks = 0; ks < 2; ++ks) {
      const int kc = ks * 4 + quad;
      bf16x8 af[2], bfr[4];
#pragma unroll
      for (int mf = 0; mf < 2; ++mf) af[mf] = TILE_AT(a_lds, wr * 32 + mf * 16 + l15, kc);
#pragma unroll
      for (int nf = 0; nf < 4; ++nf) bfr[nf] = TILE_AT(b_lds, wc * 64 + nf * 16 + l15, kc);
#pragma unroll
      for (int mf = 0; mf < 2; ++mf)
#pragma unroll
        for (int nf = 0; nf < 4; ++nf)
          acc[mf][nf] = MFMA16(af[mf], bfr[nf], acc[mf][nf]);
    }
  }
#pragma unroll
  for (int mf = 0; mf < 2; ++mf)
#pragma unroll
    for (int nf = 0; nf < 4; ++nf)
#pragma unroll
      for (int r = 0; r < 4; ++r) {
        const int nrow = nbase + wr * 32 + mf * 16 + quad * 4 + r;
        const int col = g * 128 + wc * 64 + nf * 16 + l15;
        atomicAdd(out + ((size_t)bcoord * 2048 + nrow) * 1024 + col, acc[mf][nf][r]);
      }
}

extern "C" void kernel_launch(void* const* d_in, const int* in_sizes, int n_in,
                              void* d_out, int out_size, void* d_ws, size_t ws_size,
                              hipStream_t stream) {
  const float* hs = (const float*)d_in[0];
  const float* Wq = (const float*)d_in[1];
  const float* bq = (const float*)d_in[2];
  const float* Wk = (const float*)d_in[3];
  const float* bk = (const float*)d_in[4];
  const float* Wv = (const float*)d_in[5];
  const float* bv = (const float*)d_in[6];
  float* out = (float*)d_out;

  u16* ws = (u16*)d_ws;
  u16* hsb = ws;                   // 4096x1024
  u16* Wt  = ws + 4194304;         // 3 x 1024x1024 (j-major)
  u16* Qb  = ws + 7340032;         // [b][n][1024]
  u16* Kb  = ws + 11534336;        // [b][m][1024]
  u16* Vt  = ws + 15728640;        // [b][g][h][m] = [2][8][128][2048]
  u16* Pt  = ws + 19922944;        // [b][g][n][m-half] = [2][8][2048][1024]

  k_cast<<<2048, 256, 0, stream>>>(hs, hsb, 524288);
  k_wtrans<<<1024, 256, 0, stream>>>(Wq, Wt);
  k_wtrans<<<1024, 256, 0, stream>>>(Wk, Wt + 1048576);
  k_wtrans<<<1024, 256, 0, stream>>>(Wv, Wt + 2097152);
  k_qkv<<<32 * 24, 256, 0, stream>>>(hsb, Wt, bq, bk, bv, Qb, Kb, Vt);
  k_zero<<<4096, 256, 0, stream>>>((float4*)out, 1048576);
  for (int mh = 0; mh < 2; ++mh) {
    k_score<<<1024, 512, 0, stream>>>(Qb, Kb, Pt, mh);
    k_pv<<<512, 512, 0, stream>>>(Pt, Vt, out, mh);
  }
}